// Round 5
// baseline (423.579 us; speedup 1.0000x reference)
//
#include <hip/hip_runtime.h>

#define TT 32

// ---------- bf16 helpers (OCP bfloat16, RNE) ----------
__device__ __forceinline__ float bf16_bits_to_f32(unsigned short u) {
    unsigned v = ((unsigned)u) << 16; float f; __builtin_memcpy(&f, &v, 4); return f;
}
__device__ __forceinline__ unsigned short f32_to_bf16_rne(float f) {
    unsigned u; __builtin_memcpy(&u, &f, 4);
    u += 0x7FFFu + ((u >> 16) & 1u);            // round-to-nearest-even
    return (unsigned short)(u >> 16);
}
__device__ __forceinline__ float round_bf16_f32(float f) {  // f32 -> bf16 -> f32 value
    return bf16_bits_to_f32(f32_to_bf16_rne(f));
}
// Correctly-rounded f64 -> bf16 (single rounding): round-to-odd to f32, then RNE.
__device__ __forceinline__ float f64_to_bf16_f32(double d) {
    float fz = __double2float_rz(d);
    if ((double)fz != d) {
        unsigned u; __builtin_memcpy(&u, &fz, 4); u |= 1u; __builtin_memcpy(&fz, &u, 4);
    }
    return round_bf16_f32(fz);
}
// Spread the 8 bits of b to positions 0,4,8,...,28 (Morton-4).
__device__ __forceinline__ unsigned spread4(unsigned b) {
    unsigned x = (b | (b << 12)) & 0x000F000Fu;
    x = (x | (x << 6)) & 0x03030303u;
    x = (x | (x << 3)) & 0x11111111u;
    return x;
}

// ---------- dtype detect + init ----------
__global__ void detect_and_init(const unsigned* __restrict__ spk,
                                int* __restrict__ flag, float* __restrict__ sums)
{
    unsigned w = spk[threadIdx.x];
    bool ok = (w == 0u) || (w == 0x3F800000u);
    unsigned long long vote = __ballot(ok);
    if (threadIdx.x == 0) {
        flag[0] = (vote == 0xFFFFFFFFFFFFFFFFull) ? 0 : 1;  // 0=f32, 1=bf16
        sums[0] = 0.f; sums[1] = 0.f; sums[2] = 0.f;
    }
}

// ---------- layer-0: pack spikes into SoA 4-bit index planes ----------
// Word (q, n,g,site): nibble j = spike bits of t=8q+j across the 4 cins of g.
__global__ __launch_bounds__(256)
void pack_interleave(const void* __restrict__ ginv, unsigned* __restrict__ idx0,
                     const int* __restrict__ flag)
{
    const int gid = blockIdx.x * 256 + threadIdx.x;   // 4*32*256 = 32768
    if (gid >= 32768) return;
    const int site = gid & 255;
    const int g    = (gid >> 8) & 31;
    const int n    = gid >> 13;

    unsigned m[4];
    #pragma unroll
    for (int k = 0; k < 4; ++k) {
        const size_t ebase = ((size_t)(n * 128 + 4 * g + k) * 256 + site) * TT;
        unsigned mask = 0u;
        if (flag[0]) {
            const uint4* p = (const uint4*)((const unsigned short*)ginv + ebase);
            #pragma unroll
            for (int q = 0; q < 4; ++q) {
                uint4 a = p[q];
                unsigned wd[4] = {a.x, a.y, a.z, a.w};
                #pragma unroll
                for (int mm = 0; mm < 4; ++mm) {
                    const int t = q * 8 + mm * 2;
                    mask |= (wd[mm] & 0xFFFFu) ? (1u << t)       : 0u;
                    mask |= (wd[mm] >> 16)     ? (1u << (t + 1)) : 0u;
                }
            }
        } else {
            const float4* p = (const float4*)((const float*)ginv + ebase);
            #pragma unroll
            for (int j = 0; j < 8; ++j) {
                float4 v = p[j];
                mask |= (v.x != 0.f) ? (1u << (j * 4 + 0)) : 0u;
                mask |= (v.y != 0.f) ? (1u << (j * 4 + 1)) : 0u;
                mask |= (v.z != 0.f) ? (1u << (j * 4 + 2)) : 0u;
                mask |= (v.w != 0.f) ? (1u << (j * 4 + 3)) : 0u;
            }
        }
        m[k] = mask;
    }
    #pragma unroll
    for (int q = 0; q < 4; ++q) {
        const unsigned w =  spread4((m[0] >> (8 * q)) & 0xFFu)
                         | (spread4((m[1] >> (8 * q)) & 0xFFu) << 1)
                         | (spread4((m[2] >> (8 * q)) & 0xFFu) << 2)
                         | (spread4((m[3] >> (8 * q)) & 0xFFu) << 3);
        idx0[q * 32768 + gid] = w;
    }
}

// ---------- mid-layer: masks -> SoA 4-bit index planes (plain stores) ----------
template<int C, int PLANE>   // C = channels at this interface
__global__ __launch_bounds__(256)
void pack_mid(const unsigned* __restrict__ masks, unsigned* __restrict__ idx)
{
    constexpr int G = C / 4;
    constexpr int TOT = 4 * G * PLANE;
    const int gid = blockIdx.x * 256 + threadIdx.x;
    if (gid >= TOT) return;
    const int site = gid % PLANE;
    const int g    = (gid / PLANE) % G;
    const int n    = gid / (PLANE * G);
    unsigned m[4];
    #pragma unroll
    for (int k = 0; k < 4; ++k)
        m[k] = masks[(n * C + 4 * g + k) * PLANE + site];
    #pragma unroll
    for (int q = 0; q < 4; ++q) {
        const unsigned w =  spread4((m[0] >> (8 * q)) & 0xFFu)
                         | (spread4((m[1] >> (8 * q)) & 0xFFu) << 1)
                         | (spread4((m[2] >> (8 * q)) & 0xFFu) << 2)
                         | (spread4((m[3] >> (8 * q)) & 0xFFu) << 3);
        idx[q * TOT + gid] = w;
    }
}

// ---------- fused ConvT(stride2,k3,pad1, w*2) + CUBA scan ----------
// Grid: x = site chunk, y = co, z = parity class (heavy first).
// Wave-aligned tap-slab split: block = S slabs x spb sites (slab = tid>>log2(spb),
// so each wave is site-contiguous within one slab -> LUT reads stay broadcast /
// conflict-free). MODE 0 (L1/L2): split only the 4-tap class into 2 slabs
// (per-thread tap-iters 1:2:2:2). MODE 1 (L3): S = nTap per class (exactly
// equal per-thread work, max parallelism). Slab partials combine via LDS per
// 8-t pass; slab 0 carries the scan state and writes outputs.
template<int CIN, int COUT, int MODE, bool LAST>
__global__ __launch_bounds__(256, 4)
void cuba_layer(const unsigned* __restrict__ idxIn, const void* __restrict__ wptr,
                void* __restrict__ goutv, unsigned* __restrict__ maskOut,
                int N, int Hi, int Wi, float* __restrict__ sumOut,
                const int* __restrict__ flag)
{
    constexpr int G = CIN / 4;
    constexpr int XW = (MODE == 1) ? 1536 : 1024;   // xch f64 words (worst case)
    const bool isbf = (flag[0] != 0);
    const int Ho = 2 * Hi - 1, Wo = 2 * Wi - 1;
    const int co = (int)blockIdx.y;
    const int zz = 3 - (int)blockIdx.z;          // 3=(1,1) heavy class first
    const int po = zz >> 1, pw = zz & 1;
    const int lg = po + pw;
    const int nTap = 1 << lg;
    const int nH = Hi - po, nW = Wi - pw;
    const int sites = N * nH * nW;               // sites in this class (per co)
    const int lS = (MODE == 1) ? lg : ((zz == 3) ? 1 : 0);
    const int S  = 1 << lS;                      // slabs per block
    const int spb = 256 >> lS;                   // sites per block
    const int siteBase = (int)blockIdx.x * spb;
    if (siteBase >= sites) return;               // dead block (uniform)

    // LUT[group][tap][idx]: sequential f64 sum of selected 2*w over the 4 cins.
    __shared__ double lut[G][4][16];
    __shared__ double xch[XW];                   // slab-partial exchange
    {
        const unsigned short* w16 = (const unsigned short*)wptr;
        const float* w32 = (const float*)wptr;
        const int entries = G * nTap * 16;
        for (int e = threadIdx.x; e < entries; e += 256) {
            const int idx = e & 15;
            const int tp  = (e >> 4) & (nTap - 1);
            const int g   = e >> (4 + lg);
            const int v = (po && (tp >= (pw ? 2 : 1))) ? 1 : 0;
            const int h = pw ? (tp & 1) : 0;
            const int kh = v ? 0 : (po ? 2 : 1);
            const int kw = h ? 0 : (pw ? 2 : 1);
            const int wof = kh * 3 + kw;
            double s = 0.0;
            #pragma unroll
            for (int k = 0; k < 4; ++k) {
                if ((idx >> k) & 1) {
                    const int wi = ((4 * g + k) * COUT + co) * 9 + wof;
                    const float wraw = isbf ? bf16_bits_to_f32(w16[wi]) : w32[wi];
                    s += 2.0 * (double)wraw;     // weight_scale=2 folded (exact)
                }
            }
            lut[g][tp][idx] = s;
        }
    }
    __syncthreads();

    const int slab = (int)threadIdx.x >> (8 - lS);
    const int sl   = (int)threadIdx.x & (spb - 1);
    const int siteIdx = siteBase + sl;
    const bool valid = siteIdx < sites;
    const int sIdx = valid ? siteIdx : 0;        // clamp for safe addresses

    const int b  = sIdx % nW;
    const int t1v = sIdx / nW;
    const int a  = t1v % nH;
    const int n  = t1v / nH;
    const int oh = 2 * a + po, ow = 2 * b + pw;
    const int plane = Hi * Wi;
    const int QT = N * G * plane;                // words per q-plane

    const int siteA = a * Wi + b;
    const int siteB = siteA + 1;
    const int siteC = siteA + Wi;
    const int siteD = siteC + 1;

    // Per-thread tap assignment (wave-uniform: slab and zz are wave-uniform).
    int s1 = siteA, tp1 = 0, s2 = 0, tp2 = 0;
    bool two = false;
    if (MODE == 0) {
        if (zz == 3) {                            // heavy: 2 slabs x 2 taps
            if (slab == 0) { s1 = siteA; tp1 = 0; s2 = siteB; tp2 = 1; two = true; }
            else           { s1 = siteC; tp1 = 2; s2 = siteD; tp2 = 3; two = true; }
        } else if (zz == 1) { s2 = siteB; tp2 = 1; two = true; }   // (0,1)
        else if (zz == 2)   { s2 = siteC; tp2 = 1; two = true; }   // (1,0)
        // zz==0: single tap A
    } else {
        if (zz == 1)      { if (slab == 1) { s1 = siteB; tp1 = 1; } }
        else if (zz == 2) { if (slab == 1) { s1 = siteC; tp1 = 1; } }
        else if (zz == 3) {
            if      (slab == 1) { s1 = siteB; tp1 = 1; }
            else if (slab == 2) { s1 = siteC; tp1 = 2; }
            else if (slab == 3) { s1 = siteD; tp1 = 3; }
        }
    }

    unsigned mask = 0u;
    float  curF = 0.f, volF = 0.f;
    double curD = 0.0, volD = 0.0;
    float cnt = 0.f;

    #pragma unroll 1
    for (int p = 0; p < 4; ++p) {
        double acc[8];
        #pragma unroll
        for (int j = 0; j < 8; ++j) acc[j] = 0.0;

        const unsigned* pb = idxIn + (size_t)p * QT + (size_t)(n * G) * plane;
        #pragma unroll 4
        for (int g = 0; g < G; ++g) {
            const unsigned* bp = pb + (size_t)g * plane;
            const unsigned w1 = bp[s1];
            #pragma unroll
            for (int j = 0; j < 8; ++j)
                acc[j] += lut[g][tp1][(w1 >> (4 * j)) & 0xFu];
            if (two) {
                const unsigned w2 = bp[s2];
                #pragma unroll
                for (int j = 0; j < 8; ++j)
                    acc[j] += lut[g][tp2][(w2 >> (4 * j)) & 0xFu];
            }
        }

        // Combine slab partials through LDS (order: slab 0 + 1 + 2 + 3).
        if (S > 1) {
            if (slab != 0) {
                #pragma unroll
                for (int j = 0; j < 8; ++j)
                    xch[(slab - 1) * (8 * spb) + j * spb + sl] = acc[j];
            }
            __syncthreads();
            if (slab == 0) {
                for (int s = 1; s < S; ++s)
                    #pragma unroll
                    for (int j = 0; j < 8; ++j)
                        acc[j] += xch[(s - 1) * (8 * spb) + j * spb + sl];
            }
        }

        // CUBA scan, 8 steps with carried state (slab 0 only).
        if (slab == 0) {
            if (isbf) {
                #pragma unroll
                for (int j = 0; j < 8; ++j) {
                    const int t = p * 8 + j;
                    const float z = f64_to_bf16_f32(acc[j]);
                    curF = round_bf16_f32(0.5f * curF + z);
                    volF = round_bf16_f32(0.5f * volF + curF);
                    const bool fire = (volF >= 1.0f);
                    mask |= fire ? (1u << t) : 0u;
                    volF = fire ? 0.f : volF;
                }
            } else {
                #pragma unroll
                for (int j = 0; j < 8; ++j) {
                    const int t = p * 8 + j;
                    curD = fma(0.5, curD, acc[j]);
                    volD = fma(0.5, volD, curD);
                    const bool fire = (volD >= 1.0);
                    mask |= fire ? (1u << t) : 0u;
                    volD = fire ? 0.0 : volD;
                }
            }
        }
        if (S > 1) __syncthreads();              // xch reusable next pass
    }

    if (slab == 0 && valid) {
        cnt = (float)__popc(mask);
        const int gidOut = ((n * COUT + co) * Ho + oh) * Wo + ow;
        if (LAST) {
            if (isbf) {
                uint4* ob = (uint4*)((unsigned short*)goutv + (size_t)gidOut * TT);
                #pragma unroll
                for (int q = 0; q < 4; ++q) {
                    unsigned wd[4];
                    #pragma unroll
                    for (int m2 = 0; m2 < 4; ++m2) {
                        const int t = (q * 4 + m2) * 2;
                        wd[m2] = (((mask >> t) & 1u) ? 0x3F80u : 0u)
                               | (((mask >> (t + 1)) & 1u) ? 0x3F800000u : 0u);
                    }
                    ob[q] = make_uint4(wd[0], wd[1], wd[2], wd[3]);
                }
            } else {
                float4* ob = (float4*)((float*)goutv + (size_t)gidOut * TT);
                #pragma unroll
                for (int j = 0; j < 8; ++j) {
                    float4 s4;
                    s4.x = (mask >> (j * 4 + 0)) & 1u ? 1.0f : 0.0f;
                    s4.y = (mask >> (j * 4 + 1)) & 1u ? 1.0f : 0.0f;
                    s4.z = (mask >> (j * 4 + 2)) & 1u ? 1.0f : 0.0f;
                    s4.w = (mask >> (j * 4 + 3)) & 1u ? 1.0f : 0.0f;
                    ob[j] = s4;
                }
            }
        } else {
            maskOut[gidOut] = mask;
        }
    }

    // Wave-level (64) count reduction; per-layer sums are integers < 2^24 so
    // fp32 atomic accumulation is exact.
    #pragma unroll
    for (int o = 32; o >= 1; o >>= 1) cnt += __shfl_down(cnt, o);
    if ((threadIdx.x & 63) == 0 && cnt > 0.f) atomicAdd(sumOut, cnt);
}

__global__ void finalize_counts(const float* __restrict__ sums,
                                void* __restrict__ out, const int* __restrict__ flag)
{
    int i = threadIdx.x;
    if (i < 3) {
        const float numel[3] = {7872512.f, 15239168.f, 3748096.f};
        float v = sums[i] / numel[i];
        if (flag[0]) ((unsigned short*)out)[3748096 + i] = f32_to_bf16_rne(v);
        else         ((float*)out)[3748096 + i] = v;
    }
}

extern "C" void kernel_launch(void* const* d_in, const int* in_sizes, int n_in,
                              void* d_out, int out_size, void* d_ws, size_t ws_size,
                              hipStream_t stream)
{
    const void* x  = d_in[0];  // [4,128,16,16,32] spikes (f32 or bf16)
    const void* w1 = d_in[1];  // [128,64,3,3]
    const void* w2 = d_in[2];  // [64,32,3,3]
    const void* w3 = d_in[3];  // [32,2,3,3]

    // A/B ping-pong (masks in A, index planes in B). Total ws ~ 3.81 MB.
    unsigned* bufA = (unsigned*)d_ws;          // 476,288 words
    unsigned* bufB = bufA + 476288;            // 476,288 words
    unsigned* idx0 = bufB;                     // 131,072 words used
    float* sums = (float*)(bufB + 476288);     // 3 floats
    int*   flag = (int*)(sums + 3);

    detect_and_init<<<1, 64, 0, stream>>>((const unsigned*)x, flag, sums);
    pack_interleave<<<128, 256, 0, stream>>>(x, idx0, flag);

    // L1: 128->64, 16x16 -> 31x31. heavy class: 900 sites @128/blk -> x=8
    cuba_layer<128, 64, 0, false><<<dim3(8, 64, 4), 256, 0, stream>>>(
        idx0, w1, nullptr, bufA, 4, 16, 16, sums + 0, flag);
    pack_mid<64, 961><<<241, 256, 0, stream>>>(bufA, bufB);
    // L2: 64->32, 31x31 -> 61x61. heavy class: 3600 @128/blk -> x=29
    cuba_layer<64, 32, 0, false><<<dim3(29, 32, 4), 256, 0, stream>>>(
        bufB, w2, nullptr, bufA, 4, 31, 31, sums + 1, flag);
    pack_mid<32, 3721><<<466, 256, 0, stream>>>(bufA, bufB);
    // L3: 32->2, 61x61 -> 121x121. S=nTap per class; heavy: 14400 @64/blk -> x=225
    cuba_layer<32, 2, 1, true><<<dim3(225, 2, 4), 256, 0, stream>>>(
        bufB, w3, d_out, nullptr, 4, 61, 61, sums + 2, flag);

    finalize_counts<<<1, 64, 0, stream>>>(sums, d_out, flag);
}